// Round 8
// baseline (267.031 us; speedup 1.0000x reference)
//
#include <hip/hip_runtime.h>

#define BB 2
#define LL 1536
#define DD 1024
#define HH 16
#define HDD 64
#define PP 1024

typedef __attribute__((ext_vector_type(8))) __bf16 bf16x8;
typedef __attribute__((ext_vector_type(4))) float f32x4;
typedef __attribute__((ext_vector_type(2))) float f32x2;
typedef _Float16 f16x2 __attribute__((ext_vector_type(2)));
typedef _Float16 f16x8 __attribute__((ext_vector_type(8)));

__device__ __forceinline__ unsigned short f2b(float f) {
  unsigned int x = __builtin_bit_cast(unsigned int, f);
  unsigned int r = (x + 0x7FFFu + ((x >> 16) & 1u)) >> 16;
  return (unsigned short)r;
}
__device__ __forceinline__ bf16x8 ldb8(const unsigned short* p) {
  return __builtin_bit_cast(bf16x8, *(const uint4*)p);
}
__device__ __forceinline__ f16x8 ldh8u(const unsigned int* p) {
  return __builtin_bit_cast(f16x8, *(const uint4*)p);
}
__device__ __forceinline__ unsigned int pkrtz(float lo, float hi) {
  return __builtin_bit_cast(unsigned int, __builtin_amdgcn_cvt_pkrtz(lo, hi));
}
// masked f16-pair dot accumulate: c += a.x*b.x + a.y*b.y
__device__ __forceinline__ float fdot2u(unsigned int a, unsigned int ones,
                                        float c) {
#if __has_builtin(__builtin_amdgcn_fdot2)
  return __builtin_amdgcn_fdot2(__builtin_bit_cast(f16x2, a),
                                __builtin_bit_cast(f16x2, ones), c, false);
#else
  f16x2 x = __builtin_bit_cast(f16x2, a);
  return c + (float)x.x + (float)x.y;
#endif
}
// async global->LDS, 16B per lane; lds dst = wave-uniform base + lane*16
__device__ __forceinline__ void gl_lds16(const unsigned short* g,
                                         unsigned short* l) {
  __builtin_amdgcn_global_load_lds(
      (const __attribute__((address_space(1))) void*)g,
      (__attribute__((address_space(3))) void*)l, 16, 0, 0);
}

// ---------------- prep: cast hs -> bf16 AND transpose 4x W -> WT bf16 -------
__global__ __launch_bounds__(256) void prep(
    const float* __restrict__ hs, unsigned short* __restrict__ hsb,
    const float* __restrict__ Wq, const float* __restrict__ Wk,
    const float* __restrict__ Wv, const float* __restrict__ Wo,
    unsigned short* __restrict__ WT) {
  const int bid = blockIdx.x;
  const int t = threadIdx.x;
  if (bid < 1536) {
    const int idx = bid * 2048 + t * 8;
    float4 a = *(const float4*)(hs + idx);
    float4 b = *(const float4*)(hs + idx + 4);
    uint4 u;
    u.x = (unsigned int)f2b(a.x) | ((unsigned int)f2b(a.y) << 16);
    u.y = (unsigned int)f2b(a.z) | ((unsigned int)f2b(a.w) << 16);
    u.z = (unsigned int)f2b(b.x) | ((unsigned int)f2b(b.y) << 16);
    u.w = (unsigned int)f2b(b.z) | ((unsigned int)f2b(b.w) << 16);
    *(uint4*)(hsb + idx) = u;
  } else {
    __shared__ float tile[64][68];
    const int t2 = bid - 1536;
    const int z = t2 >> 8;
    const int bx = t2 & 15, by = (t2 >> 4) & 15;
    const float* W = (z == 0) ? Wq : (z == 1) ? Wk : (z == 2) ? Wv : Wo;
    unsigned short* O = WT + (size_t)z * 1024 * 1024;
    const int r0 = by * 64;  // k rows
    const int c0 = bx * 64;  // n cols
#pragma unroll
    for (int i = 0; i < 4; ++i) {
      const int row = (t >> 4) + i * 16;
      const int col = (t & 15) * 4;
      *(float4*)&tile[row][col] =
          *(const float4*)&W[(size_t)(r0 + row) * 1024 + c0 + col];
    }
    __syncthreads();
#pragma unroll
    for (int i = 0; i < 4; ++i) {
      const int n = (t >> 4) + i * 16;
      const int k4 = (t & 15) * 4;
      uint2 u;
      u.x = (unsigned int)f2b(tile[k4 + 0][n]) |
            ((unsigned int)f2b(tile[k4 + 1][n]) << 16);
      u.y = (unsigned int)f2b(tile[k4 + 2][n]) |
            ((unsigned int)f2b(tile[k4 + 3][n]) << 16);
      *(uint2*)&O[(size_t)(c0 + n) * 1024 + r0 + k4] = u;
    }
  }
}

// ---------------- bf16 MFMA GEMM: C[M,1024] = A[M,1024] @ Bt[1024,1024]^T ----
// 128x128 tile, BK=32, 4 waves, 4x4 MFMA/wave.
// R8: double-buffered LDS + ONE barrier per K-iter (was 2 barriers, zero
// prefetch -> every iter drained vmcnt(0) with all waves idle; ~300-900cy
// HBM/L2 latency fully exposed vs ~80cy MFMA/wave/iter). Now: issue next
// tile's global_load_lds into buf^1, compute buf, single barrier (drains
// loads + protects buf reuse) — the guide's proven "minimum 2-phase".
// LDS 32KB/block (2x8KB x2 arrays) -> still ~5 blocks/CU.
// MODE 0: Q fragment-linear *0.125. MODE 1: K fragment-linear. MODE 2: V
// fragment-linear (f16 — PV consumes f16). MODE 3: fp32 row-major.
template <int MODE>
__device__ __forceinline__ void gemm_mfma_body(
    const unsigned short* __restrict__ A, const unsigned short* __restrict__ Bt,
    const float* __restrict__ bias, void* __restrict__ Cout, const int m0,
    const int n0) {
  __shared__ unsigned short As[2 * 128 * 32];
  __shared__ unsigned short Bs[2 * 128 * 32];
  const int t = threadIdx.x;
  const int lane = t & 63;
  const int w = t >> 6;
  const int quad = lane >> 4;
  const int lc = lane & 15;

  const int sr = lane >> 2;       // row within 16-row group
  const int sk = (lane & 3) * 8;  // k element offset
  const unsigned short* ga0 = A + (size_t)(m0 + w * 32 + sr) * 1024 + sk;
  const unsigned short* ga1 = ga0 + 16 * 1024;
  const unsigned short* gb0 = Bt + (size_t)(n0 + w * 32 + sr) * 1024 + sk;
  const unsigned short* gb1 = gb0 + 16 * 1024;
  unsigned short* const laA = As + w * 1024;
  unsigned short* const laB = Bs + w * 1024;

  const int mrow0 = (w >> 1) * 64, ncol0 = (w & 1) * 64;

  f32x4 acc[4][4];
#pragma unroll
  for (int i = 0; i < 4; ++i)
#pragma unroll
    for (int j = 0; j < 4; ++j) acc[i][j] = (f32x4){0.f, 0.f, 0.f, 0.f};

  auto stage = [&](int buf, int k0) {
    unsigned short* a = laA + buf * 4096;
    unsigned short* bp = laB + buf * 4096;
    gl_lds16(ga0 + k0, a);
    gl_lds16(ga1 + k0, a + 512);
    gl_lds16(gb0 + k0, bp);
    gl_lds16(gb1 + k0, bp + 512);
  };
  auto compute = [&](int buf) {
    const unsigned short* Ab = As + buf * 4096;
    const unsigned short* Bb = Bs + buf * 4096;
    bf16x8 af[4], bfr[4];
#pragma unroll
    for (int i = 0; i < 4; ++i)
      af[i] = ldb8(&Ab[(mrow0 + i * 16 + lc) * 32 + quad * 8]);
#pragma unroll
    for (int j = 0; j < 4; ++j)
      bfr[j] = ldb8(&Bb[(ncol0 + j * 16 + lc) * 32 + quad * 8]);
#pragma unroll
    for (int i = 0; i < 4; ++i)
#pragma unroll
      for (int j = 0; j < 4; ++j)
        acc[i][j] = __builtin_amdgcn_mfma_f32_16x16x32_bf16(af[i], bfr[j],
                                                            acc[i][j], 0, 0, 0);
  };

  stage(0, 0);
  __syncthreads();  // prologue tile resident
  for (int it = 0; it < 32; it += 2) {
    stage(1, (it + 1) * 32);  // prefetch while computing buf0
    compute(0);
    __syncthreads();  // buf1 ready; buf0 reads done (safe to overwrite)
    if (it + 2 < 32) stage(0, (it + 2) * 32);
    compute(1);
    __syncthreads();
  }

#pragma unroll
  for (int i = 0; i < 4; ++i) {
    const int row0 = m0 + mrow0 + i * 16 + quad * 4;  // rows row0..row0+3
#pragma unroll
    for (int jj = 0; jj < 4; ++jj) {
      const int col = n0 + ncol0 + jj * 16 + lc;
      const float bz = bias[col];
      float o[4];
#pragma unroll
      for (int r = 0; r < 4; ++r) o[r] = acc[i][jj][r] + bz;
      if constexpr (MODE == 0) {
        // Q fragment-linear: QF[(bh*96+qt)*2+f][qk*16+m][8], scale 0.125
        const int bb = row0 / LL;
        const int ql = row0 - bb * LL;  // q local; %16 == quad*4
        const int qt = ql >> 4;
        const int m = ql & 15;
        const int hh = col >> 6;
        const int hd = col & 63;
        const int f = hd >> 5;
        const int qk = (hd >> 3) & 3;
        const int j = hd & 7;
        unsigned short* QF = (unsigned short*)Cout;
        const size_t base = (((size_t)(bb * HH + hh) * 96 + qt) * 2 + f) * 512 +
                            (qk * 16 + m) * 8 + j;
#pragma unroll
        for (int r = 0; r < 4; ++r) QF[base + r * 8] = f2b(o[r] * 0.125f);
      } else if constexpr (MODE == 1) {
        // K fragment-linear: key=row, tile=key/16, m=key%16, col-> f,qk,j
        const int bb = row0 / LL;
        const int kl = row0 - bb * LL;  // key local, %16 == quad*4
        const int ktl = kl >> 4;
        const int m = kl & 15;
        const int hh = col >> 6;
        const int hd = col & 63;
        const int f = hd >> 5;
        const int qk = (hd >> 3) & 3;
        const int j = hd & 7;
        unsigned short* KF = (unsigned short*)Cout;
        const size_t base =
            (((size_t)(bb * HH + hh) * 96 + ktl) * 2 + f) * 512 +
            (qk * 16 + m) * 8 + j;
#pragma unroll
        for (int r = 0; r < 4; ++r) KF[base + r * 8] = f2b(o[r]);
      } else if constexpr (MODE == 2) {
        // V fragment-linear, f16: r=0..3 -> 4 consecutive j -> one uint2 store
        const int bb = row0 / LL;
        const int kl = row0 - bb * LL;  // key local of r=0
        const int hh = col >> 6;
        const int hd = col & 63;
        const int hg = hd >> 4;
        const int lcv = hd & 15;
        const int tile = (kl >> 5);  // gg*2 + c
        const int qv = (kl >> 3) & 3;
        const int j0 = kl & 7;  // 0 or 4
        unsigned short* VF = (unsigned short*)Cout;
        const size_t base = (((size_t)(bb * HH + hh) * 4 + hg) * 48 + tile) * 512 +
                            (qv * 16 + lcv) * 8 + j0;
        uint2 u;
        u.x = pkrtz(o[0], o[1]);
        u.y = pkrtz(o[2], o[3]);
        *(uint2*)&VF[base] = u;
      } else {
#pragma unroll
        for (int r = 0; r < 4; ++r)
          ((float*)Cout)[(size_t)(row0 + r) * 1024 + col] = o[r];
      }
    }
  }
}

// XCD-chunked bijective swizzle for a 192-block (8x24) grid slice: default
// round-robin puts the same bx on each XCD (A streams 6.3MB > 4MB L2, thrash);
// chunked gives each XCD a 3-row x 8-col band (~2.8MB, L2-fits).
__device__ __forceinline__ void swz192(int& m0, int& n0) {
  const int lin = blockIdx.y * 8 + blockIdx.x;  // 0..191, x fastest
  const int swz = (lin & 7) * 24 + (lin >> 3);
  m0 = (swz >> 3) * 128;
  n0 = (swz & 7) * 128;
}

__global__ __launch_bounds__(256) void qkv_gemm(
    const unsigned short* __restrict__ hsb,
    const unsigned short* __restrict__ WT, const float* __restrict__ bq,
    const float* __restrict__ bk, const float* __restrict__ bv,
    unsigned short* __restrict__ QF, unsigned short* __restrict__ KF,
    unsigned short* __restrict__ VF) {
  int m0, n0;
  swz192(m0, n0);
  if (blockIdx.z == 0) {
    gemm_mfma_body<0>(hsb, WT, bq, QF, m0, n0);
  } else if (blockIdx.z == 1) {
    gemm_mfma_body<1>(hsb, WT + 1024 * 1024, bk, KF, m0, n0);
  } else {
    gemm_mfma_body<2>(hsb, WT + 2 * 1024 * 1024, bv, VF, m0, n0);
  }
}

__global__ __launch_bounds__(256) void out_gemm(
    const unsigned short* __restrict__ ctxb,
    const unsigned short* __restrict__ WoT, const float* __restrict__ bo,
    float* __restrict__ out) {
  int m0, n0;
  swz192(m0, n0);
  gemm_mfma_body<3>(ctxb, WoT, bo, out, m0, n0);
}

// ---------------- fused attention, single transposed layout ------------------
// (R7 body, unchanged this round for attribution.)
// 1024 threads / 16 waves. Wave w owns key-tiles 6w..6w+5 (keys 96w..96w+95);
// lane holds q=lc, keys 16j+4*quad+r. Slot s>=1 of P2u holds p^T (f16) for
// key-tile s-1; slot 0 = zero halo. LDS P2u is the sole p master.
// Row stride 12 u32 (48B): 8 distinct 16B-aligned bank starts x 2 lanes =
// conflict-free b128/b64 phases; spare cols 8..11 hold PV partials.
__global__ __launch_bounds__(1024)
    __attribute__((amdgpu_waves_per_eu(8))) void attn_kernel(
        const unsigned short* __restrict__ QF,
        const unsigned short* __restrict__ KF,
        const unsigned short* __restrict__ VF, const int* __restrict__ mask,
        const float* __restrict__ kernel_w, unsigned short* __restrict__ ctxb) {
  __shared__ __align__(16) unsigned int P2u[97 * 192];  // 74,496 B, rows 12 u32
  __shared__ unsigned int kvb[48];                      // packed key-valid bits
  __shared__ float red_a[16][16];
  __shared__ float red_b[16][16];
  __shared__ float wext[48];  // band weights, wext[16+d]=wr[d], else 0

  const int t = threadIdx.x;
  const int lane = t & 63;
  const int w = t >> 6;        // wave id 0..15
  const int quad = lane >> 4;  // 0..3
  const int lc = lane & 15;
  const int b = blockIdx.z, h = blockIdx.y;
  const int q0 = blockIdx.x * 16;

  // key-valid bitmask via per-wave ballot
  {
    unsigned long long bal = __ballot(mask[b * LL + t] > 0);  // keys 0..1023
    if (lane == 0) {
      kvb[2 * w] = (unsigned int)bal;
      kvb[2 * w + 1] = (unsigned int)(bal >> 32);
    }
  }
  if (w < 8) {  // keys 1024..1535 (wave-uniform branch)
    unsigned long long bal = __ballot(mask[b * LL + 1024 + t] > 0);
    if (lane == 0) {
      kvb[32 + 2 * w] = (unsigned int)bal;
      kvb[33 + 2 * w] = (unsigned int)(bal >> 32);
    }
  }
  // zero halo slot 0 of P2u (192 u32 incl. spare cols)
  if (t < 192) P2u[t] = 0;
  // reversed-softmax smoothing weights -> extended band array
  {
    float k0 = kernel_w[0], k1 = kernel_w[1], k2 = kernel_w[2],
          k3 = kernel_w[3], k4 = kernel_w[4];
    float km = fmaxf(fmaxf(fmaxf(k0, k1), fmaxf(k2, k3)), k4);
    float e0 = __expf(k0 - km), e1 = __expf(k1 - km), e2 = __expf(k2 - km),
          e3 = __expf(k3 - km), e4 = __expf(k4 - km);
    float es = e0 + e1 + e2 + e3 + e4;
    // wr[d] = softmax(w)[4-d]; ps[i] = sum_d wr[d]*p[i-d]
    if (t < 48) {
      float v = 0.f;
      if (t == 16) v = e4 / es;
      if (t == 17) v = e3 / es;
      if (t == 18) v = e2 / es;
      if (t == 19) v = e1 / es;
      if (t == 20) v = e0 / es;
      wext[t] = v;
    }
  }
  __syncthreads();  // S1: kvb, halo, wext visible

  // constant band A-fragment (f16): A[m=lc][k=quad*8+jj] = wr[lc+16-k]
  f16x8 afb;
  {
    const int kb = lc + 32 - quad * 8;  // wext index for jj=0
    uint4 uu;
    uu.x = pkrtz(wext[kb], wext[kb - 1]);
    uu.y = pkrtz(wext[kb - 2], wext[kb - 3]);
    uu.z = pkrtz(wext[kb - 4], wext[kb - 5]);
    uu.w = pkrtz(wext[kb - 6], wext[kb - 7]);
    afb = __builtin_bit_cast(f16x8, uu);
  }

  // ---- phase 1+2 fused: scores MFMA -> masked exp -> pack -> store e~.
  unsigned int* const pwb = &P2u[((6 * w + 1) * 16 + lc) * 12 + 2 * quad];
  unsigned int mA = 0u;
  {
    const unsigned short* qfb =
        QF + (((size_t)(b * HH + h) * 96 + (q0 >> 4)) * 2) * 512 + lane * 8;
    const bf16x8 qb0 = ldb8(qfb);
    const bf16x8 qb1 = ldb8(qfb + 512);
    const unsigned short* kfb =
        KF + (((size_t)(b * HH + h) * 96 + 6 * w) * 2) * 512 + lane * 8;
    float s = 0.f;
#pragma unroll
    for (int j = 0; j < 6; ++j) {
      bf16x8 ka0 = ldb8(kfb + j * 1024);
      bf16x8 ka1 = ldb8(kfb + j * 1024 + 512);
      f32x4 acc = {0.f, 0.f, 0.f, 0.f};
      acc = __builtin_amdgcn_mfma_f32_16x16x32_bf16(ka0, qb0, acc, 0, 0, 0);
      acc = __builtin_amdgcn_mfma_f32_16x16x32_bf16(ka1, qb1, acc, 0, 0, 0);
      const int kb16 = 16 * j + 4 * quad;  // (96w + kb16) & 31 == kb16 & 31
      const unsigned int w4 = (kvb[3 * w + (kb16 >> 5)] >> (kb16 & 31)) & 0xFu;
      mA |= w4 << (4 * j);
      float e0 = (w4 & 1u) ? __expf(acc[0]) : 0.f;
      float e1 = (w4 & 2u) ? __expf(acc[1]) : 0.f;
      float e2 = (w4 & 4u) ? __expf(acc[2]) : 0.f;
      float e3 = (w4 & 8u) ? __expf(acc[3]) : 0.f;
      uint2 u;
      u.x = pkrtz(e0, e1);
      u.y = pkrtz(e2, e3);
      *(uint2*)(pwb + j * 192) = u;
      s += (e0 + e1) + (e2 + e3);
    }
    s += __shfl_xor(s, 16, 64);
    s += __shfl_xor(s, 32, 64);
    if (lane < 16) red_a[w][lane] = s;
  }
  __syncthreads();  // S3: P2u (e~) + red_a visible

  // ---- phase 3: 3 diffusion steps; smooth = f16 MFMA vs constant band frag.
  const unsigned int ones2 = 0x3C003C00u;  // f16 {1,1}
  const unsigned int* const prb =
      &P2u[((6 * w + (quad >> 1)) * 16 + lc) * 12 + (quad & 1) * 4];
  float inv = 0.f;
#pragma unroll
  for (int step = 0; step < 3; ++step) {
    unsigned int s_pk[12];  // masked smoothed p, packed f16 pairs
    float sum = 0.f;
#pragma unroll
    for (int j = 0; j < 6; ++j) {
      f16x8 bfr = ldh8u(prb + j * 192);
      f32x4 z = {0.f, 0.f, 0.f, 0.f};
      f32x4 ps = __builtin_amdgcn_mfma_f32_16x16x32_f16(afb, bfr, z, 0, 0, 0);
      const unsigned int w4 = (mA >> (4 * j)) & 0xFu;
      float p0 = (w4 & 1u) ? ps[0] : 0.f;
      float p1 = (w4 & 2u) ? ps[1] : 0.f;
      float p2 = (w4 & 4u) ? ps[2] : 0.f;
      float p3 = (w4 & 8u) ? ps[3] : 0.f;
      s_pk[2 * j] = pkrtz(p0, p1);
      s_pk[2 * j + 1] = pkrtz(p2, p3);
      sum = fdot2u(s_pk[2 * j], ones2, sum);
      sum = fdot2u(s_pk[2 * j + 1], ones2, sum);
    }
    sum += __shfl_xor(sum, 16, 64);
    sum += __shfl_xor(sum, 32, 64);
    if (step == 0) {  // softmax denom (red_a stable until step 1's write)
      float tot0 = 0.f;
#pragma unroll
      for (int ww = 0; ww < 16; ++ww) tot0 += red_a[ww][lc];
      inv = 1.f / tot0;
    }
    if (lane < 16) {
      if (step & 1)
        red_a[w][lane] = sum;
      else
        red_b[w][lane] = sum;
    }
    __syncthreads();  // B1: all P2u reads of this step done; partials ready
    float tot = 0.f;
#pragma unroll
    for (int ww = 0; ww < 16; ++ww)
      tot += (step & 1) ? red_a[ww][lc] : red_b[ww][lc];
    // new_p = p_old*cmul + (s_pk*cinv)*cps
    f16x2 cmul, cinv, cps;
    if (step == 0) {
      const float sps = tot * inv;  // sum(ps) in normalized domain
      const float pinv = 0.02f / (sps + 1e-9f);
      const _Float16 hc = (_Float16)(0.98f * inv);
      const _Float16 hi = (_Float16)inv;
      const _Float16 hp = (_Float16)pinv;
      cmul = (f16x2){hc, hc};
      cinv = (f16x2){hi, hi};
      cps = (f16x2){hp, hp};
    } else {
      const float pinv = 0.02f / (tot + 1e-9f);
      const _Float16 hp = (_Float16)pinv;
      cmul = (f16x2){(_Float16)0.98f, (_Float16)0.98f};
      cinv = (f16x2){(_Float16)1.f, (_Float16)1.f};
      cps = (f16x2){hp, hp};
    }
#pragma unroll
    for (int j = 0; j < 6; ++j) {
      uint2 po = *(const uint2*)(pwb + j * 192);  // own slots only
      f16x2 p0h = __builtin_bit_cast(f16x2, po.x);
      f16x2 p1h = __builtin_bit_cast(f16x2, po.y);
      f16x2 s0h = __builtin_bit_cast(f16x2, s_pk[2 * j]);
      f16x2 s1h = __builtin_bit_cast(f16x2, s_pk[2 * j + 1]);
      p0h = p0h * cmul + (s0h * cinv) * cps;
      p1h = p1h * cmul + (s1h * cinv) * cps;
      uint2 nu;
      nu.x = __builtin_bit_cast(unsigned int, p0h);
      nu.y = __builtin_bit_cast(unsigned int, p1h);
      *(uint2*)(pwb + j * 192) = nu;
    }
    __syncthreads();  // B2: new p visible for next step / PV
  }

  // ---- phase 4: PV via f16 MFMA; A = p frags from P2u, B = V frags (f16).
  // 4 col-groups (cg=w&3, hd cols cg*16+lc) x 4 key-quarters (kt=w>>2,
  // 12 windows of 32 keys each). Partials exchanged through the SPARE
  // columns (u32 8..11) of P2u rows — disjoint from data cols, no barrier
  // needed between PV reads and partial stores.
  const int cg = w & 3;
  const int kt = w >> 2;
  const int cidx = cg * 16 + lc;
  const int li = (cg * 4 + quad) * 16 + lc;  // 0..255
  const unsigned short* vfb =
      VF + ((((size_t)(b * HH + h) * 4 + cg) * 48 + 12 * kt) * 512) + lane * 8;
  const unsigned int* const pvb =
      &P2u[((24 * kt + 1 + (quad >> 1)) * 16 + lc) * 12 + (quad & 1) * 4];
  f32x4 oacc = {0.f, 0.f, 0.f, 0.f};
#pragma unroll
  for (int g = 0; g < 6; ++g) {
#pragma unroll
    for (int c = 0; c < 2; ++c) {
      f16x8 pa = ldh8u(pvb + (4 * g + 2 * c) * 192);
      f16x8 vf =
          __builtin_bit_cast(f16x8, *(const uint4*)(vfb + (2 * g + c) * 512));
      oacc = __builtin_amdgcn_mfma_f32_16x16x32_f16(pa, vf, oacc, 0, 0, 0);
    }
  }
  if (kt > 0) {
    float* sp = (float*)&P2u[((kt - 1) * 256 + li) * 12 + 8];
    *(float4*)sp = make_float4(oacc[0], oacc[1], oacc[2], oacc[3]);
  }
  __syncthreads();  // partials visible (PV data reads already done per-wave)
  if (kt == 0) {
    float o[4] = {oacc[0], oacc[1], oacc[2], oacc[3]};
#pragma unroll
    for (int p = 0; p < 3; ++p) {
      const float4 prr = *(const float4*)&P2u[(p * 256 + li) * 12 + 8];
      o[0] += prr.x;
      o[1] += prr.y;
      o[2] += prr.z;
      o[3] += prr.w;
    }
#pragma unroll
    for (int r = 0; r < 4; ++r)
      ctxb[((size_t)(b * LL + q0 + quad * 4 + r)) * PP + h * HDD + cidx] =
          f2b(o[r]);
  }
}

extern "C" void kernel_launch(void* const* d_in, const int* in_sizes, int n_in,
                              void* d_out, int out_size, void* d_ws,
                              size_t ws_size, hipStream_t stream) {
  const float* hs = (const float*)d_in[0];
  const int* mask = (const int*)d_in[1];
  const float* Wq = (const float*)d_in[2];
  const float* bq = (const float*)d_in[3];
  const float* Wk = (const float*)d_in[4];
  const float* bk = (const float*)d_in[5];
  const float* Wv = (const float*)d_in[6];
  const float* bv = (const float*)d_in[7];
  const float* Wo = (const float*)d_in[8];
  const float* bo = (const float*)d_in[9];
  const float* kw = (const float*)d_in[10];

  const size_t NBLP = (size_t)BB * LL * PP;    // 3,145,728 elems
  unsigned short* QF = (unsigned short*)d_ws;  // Q fragment-linear
  unsigned short* KF = QF + NBLP;              // K fragment-linear
  unsigned short* VF = KF + NBLP;              // V fragment-linear (f16)
  unsigned short* ctxb = VF + NBLP;            // bf16 ctx
  unsigned short* hsb = ctxb + NBLP;
  unsigned short* WT = hsb + NBLP;  // 4 x [1024][1024] bf16 (n-major)

  dim3 blk(256);
  prep<<<dim3(2560), blk, 0, stream>>>(hs, hsb, Wq, Wk, Wv, Wo, WT);
  qkv_gemm<<<dim3(8, 24, 3), blk, 0, stream>>>(hsb, WT, bq, bk, bv, QF, KF, VF);
  attn_kernel<<<dim3(96, 16, 2), dim3(1024), 0, stream>>>(QF, KF, VF, mask, kw,
                                                          ctxb);
  out_gemm<<<dim3(8, 24, 1), blk, 0, stream>>>(ctxb, WT + 3 * 1024 * 1024, bo,
                                               (float*)d_out);
}

// Round 9
// 238.659 us; speedup vs baseline: 1.1189x; 1.1189x over previous
//
#include <hip/hip_runtime.h>

#define BB 2
#define LL 1536
#define DD 1024
#define HH 16
#define HDD 64
#define PP 1024

typedef __attribute__((ext_vector_type(8))) __bf16 bf16x8;
typedef __attribute__((ext_vector_type(4))) float f32x4;
typedef __attribute__((ext_vector_type(2))) float f32x2;
typedef _Float16 f16x2 __attribute__((ext_vector_type(2)));
typedef _Float16 f16x8 __attribute__((ext_vector_type(8)));

__device__ __forceinline__ unsigned short f2b(float f) {
  unsigned int x = __builtin_bit_cast(unsigned int, f);
  unsigned int r = (x + 0x7FFFu + ((x >> 16) & 1u)) >> 16;
  return (unsigned short)r;
}
__device__ __forceinline__ bf16x8 ldb8(const unsigned short* p) {
  return __builtin_bit_cast(bf16x8, *(const uint4*)p);
}
__device__ __forceinline__ f16x8 ldh8u(const unsigned int* p) {
  return __builtin_bit_cast(f16x8, *(const uint4*)p);
}
__device__ __forceinline__ unsigned int pkrtz(float lo, float hi) {
  return __builtin_bit_cast(unsigned int, __builtin_amdgcn_cvt_pkrtz(lo, hi));
}
// masked f16-pair dot accumulate: c += a.x*b.x + a.y*b.y
__device__ __forceinline__ float fdot2u(unsigned int a, unsigned int ones,
                                        float c) {
#if __has_builtin(__builtin_amdgcn_fdot2)
  return __builtin_amdgcn_fdot2(__builtin_bit_cast(f16x2, a),
                                __builtin_bit_cast(f16x2, ones), c, false);
#else
  f16x2 x = __builtin_bit_cast(f16x2, a);
  return c + (float)x.x + (float)x.y;
#endif
}
// async global->LDS, 16B per lane; lds dst = wave-uniform base + lane*16
__device__ __forceinline__ void gl_lds16(const unsigned short* g,
                                         unsigned short* l) {
  __builtin_amdgcn_global_load_lds(
      (const __attribute__((address_space(1))) void*)g,
      (__attribute__((address_space(3))) void*)l, 16, 0, 0);
}

// ---------------- prep: cast hs -> bf16 AND transpose 4x W -> WT bf16 -------
__global__ __launch_bounds__(256) void prep(
    const float* __restrict__ hs, unsigned short* __restrict__ hsb,
    const float* __restrict__ Wq, const float* __restrict__ Wk,
    const float* __restrict__ Wv, const float* __restrict__ Wo,
    unsigned short* __restrict__ WT) {
  const int bid = blockIdx.x;
  const int t = threadIdx.x;
  if (bid < 1536) {
    const int idx = bid * 2048 + t * 8;
    float4 a = *(const float4*)(hs + idx);
    float4 b = *(const float4*)(hs + idx + 4);
    uint4 u;
    u.x = (unsigned int)f2b(a.x) | ((unsigned int)f2b(a.y) << 16);
    u.y = (unsigned int)f2b(a.z) | ((unsigned int)f2b(a.w) << 16);
    u.z = (unsigned int)f2b(b.x) | ((unsigned int)f2b(b.y) << 16);
    u.w = (unsigned int)f2b(b.z) | ((unsigned int)f2b(b.w) << 16);
    *(uint4*)(hsb + idx) = u;
  } else {
    __shared__ float tile[64][68];
    const int t2 = bid - 1536;
    const int z = t2 >> 8;
    const int bx = t2 & 15, by = (t2 >> 4) & 15;
    const float* W = (z == 0) ? Wq : (z == 1) ? Wk : (z == 2) ? Wv : Wo;
    unsigned short* O = WT + (size_t)z * 1024 * 1024;
    const int r0 = by * 64;  // k rows
    const int c0 = bx * 64;  // n cols
#pragma unroll
    for (int i = 0; i < 4; ++i) {
      const int row = (t >> 4) + i * 16;
      const int col = (t & 15) * 4;
      *(float4*)&tile[row][col] =
          *(const float4*)&W[(size_t)(r0 + row) * 1024 + c0 + col];
    }
    __syncthreads();
#pragma unroll
    for (int i = 0; i < 4; ++i) {
      const int n = (t >> 4) + i * 16;
      const int k4 = (t & 15) * 4;
      uint2 u;
      u.x = (unsigned int)f2b(tile[k4 + 0][n]) |
            ((unsigned int)f2b(tile[k4 + 1][n]) << 16);
      u.y = (unsigned int)f2b(tile[k4 + 2][n]) |
            ((unsigned int)f2b(tile[k4 + 3][n]) << 16);
      *(uint2*)&O[(size_t)(c0 + n) * 1024 + r0 + k4] = u;
    }
  }
}

// ---------------- bf16 MFMA GEMM: C[M,1024] = A[M,1024] @ Bt[1024,1024]^T ----
// 128x128 tile, BK=32, 4 waves, 4x4 MFMA/wave.
// R9: REVERTED to the R7 single-buffer 2-barrier m97-structure. R8's dbuf
// "2-phase" regressed +30us total — consistent with guide data: m97-structure
// = 874 TF at 128^2 vs plain dbuf 2-phase ~655-682 (m230/m248); with ~4
// blocks/CU co-resident, inter-block TLP (m114) already hides the barrier
// drain, and dbuf adds an inline per-wave vmcnt dependency instead.
// MODE 0: Q fragment-linear *0.125. MODE 1: K fragment-linear. MODE 2: V
// fragment-linear (f16 — PV consumes f16). MODE 3: fp32 row-major.
template <int MODE>
__device__ __forceinline__ void gemm_mfma_body(
    const unsigned short* __restrict__ A, const unsigned short* __restrict__ Bt,
    const float* __restrict__ bias, void* __restrict__ Cout) {
  __shared__ unsigned short As[128 * 32];
  __shared__ unsigned short Bs[128 * 32];
  const int t = threadIdx.x;
  const int lane = t & 63;
  const int w = t >> 6;
  const int quad = lane >> 4;
  const int lc = lane & 15;
  const int m0 = blockIdx.y * 128, n0 = blockIdx.x * 128;

  const int sr = lane >> 2;       // row within 16-row group
  const int sk = (lane & 3) * 8;  // k element offset
  const unsigned short* ga0 = A + (size_t)(m0 + w * 32 + sr) * 1024 + sk;
  const unsigned short* ga1 = ga0 + 16 * 1024;
  const unsigned short* gb0 = Bt + (size_t)(n0 + w * 32 + sr) * 1024 + sk;
  const unsigned short* gb1 = gb0 + 16 * 1024;
  unsigned short* la0 = As + w * 1024;
  unsigned short* la1 = As + w * 1024 + 512;
  unsigned short* lb0 = Bs + w * 1024;
  unsigned short* lb1 = Bs + w * 1024 + 512;

  const int mrow0 = (w >> 1) * 64, ncol0 = (w & 1) * 64;

  f32x4 acc[4][4];
#pragma unroll
  for (int i = 0; i < 4; ++i)
#pragma unroll
    for (int j = 0; j < 4; ++j) acc[i][j] = (f32x4){0.f, 0.f, 0.f, 0.f};

  for (int k0 = 0; k0 < 1024; k0 += 32) {
    __syncthreads();  // previous iter's ds_reads done before overwrite
    gl_lds16(ga0 + k0, la0);
    gl_lds16(ga1 + k0, la1);
    gl_lds16(gb0 + k0, lb0);
    gl_lds16(gb1 + k0, lb1);
    __syncthreads();  // staged data visible
    bf16x8 af[4], bfr[4];
#pragma unroll
    for (int i = 0; i < 4; ++i)
      af[i] = ldb8(&As[(mrow0 + i * 16 + lc) * 32 + quad * 8]);
#pragma unroll
    for (int j = 0; j < 4; ++j)
      bfr[j] = ldb8(&Bs[(ncol0 + j * 16 + lc) * 32 + quad * 8]);
#pragma unroll
    for (int i = 0; i < 4; ++i)
#pragma unroll
      for (int j = 0; j < 4; ++j)
        acc[i][j] = __builtin_amdgcn_mfma_f32_16x16x32_bf16(af[i], bfr[j],
                                                            acc[i][j], 0, 0, 0);
  }

#pragma unroll
  for (int i = 0; i < 4; ++i) {
    const int row0 = m0 + mrow0 + i * 16 + quad * 4;  // rows row0..row0+3
#pragma unroll
    for (int jj = 0; jj < 4; ++jj) {
      const int col = n0 + ncol0 + jj * 16 + lc;
      const float bz = bias[col];
      float o[4];
#pragma unroll
      for (int r = 0; r < 4; ++r) o[r] = acc[i][jj][r] + bz;
      if constexpr (MODE == 0) {
        // Q fragment-linear: QF[(bh*96+qt)*2+f][qk*16+m][8], scale 0.125
        const int bb = row0 / LL;
        const int ql = row0 - bb * LL;  // q local; %16 == quad*4
        const int qt = ql >> 4;
        const int m = ql & 15;
        const int hh = col >> 6;
        const int hd = col & 63;
        const int f = hd >> 5;
        const int qk = (hd >> 3) & 3;
        const int j = hd & 7;
        unsigned short* QF = (unsigned short*)Cout;
        const size_t base = (((size_t)(bb * HH + hh) * 96 + qt) * 2 + f) * 512 +
                            (qk * 16 + m) * 8 + j;
#pragma unroll
        for (int r = 0; r < 4; ++r) QF[base + r * 8] = f2b(o[r] * 0.125f);
      } else if constexpr (MODE == 1) {
        // K fragment-linear: key=row, tile=key/16, m=key%16, col-> f,qk,j
        const int bb = row0 / LL;
        const int kl = row0 - bb * LL;  // key local, %16 == quad*4
        const int ktl = kl >> 4;
        const int m = kl & 15;
        const int hh = col >> 6;
        const int hd = col & 63;
        const int f = hd >> 5;
        const int qk = (hd >> 3) & 3;
        const int j = hd & 7;
        unsigned short* KF = (unsigned short*)Cout;
        const size_t base =
            (((size_t)(bb * HH + hh) * 96 + ktl) * 2 + f) * 512 +
            (qk * 16 + m) * 8 + j;
#pragma unroll
        for (int r = 0; r < 4; ++r) KF[base + r * 8] = f2b(o[r]);
      } else if constexpr (MODE == 2) {
        // V fragment-linear, f16: r=0..3 -> 4 consecutive j -> one uint2 store
        const int bb = row0 / LL;
        const int kl = row0 - bb * LL;  // key local of r=0
        const int hh = col >> 6;
        const int hd = col & 63;
        const int hg = hd >> 4;
        const int lcv = hd & 15;
        const int tile = (kl >> 5);  // gg*2 + c
        const int qv = (kl >> 3) & 3;
        const int j0 = kl & 7;  // 0 or 4
        unsigned short* VF = (unsigned short*)Cout;
        const size_t base = (((size_t)(bb * HH + hh) * 4 + hg) * 48 + tile) * 512 +
                            (qv * 16 + lcv) * 8 + j0;
        uint2 u;
        u.x = pkrtz(o[0], o[1]);
        u.y = pkrtz(o[2], o[3]);
        *(uint2*)&VF[base] = u;
      } else {
#pragma unroll
        for (int r = 0; r < 4; ++r)
          ((float*)Cout)[(size_t)(row0 + r) * 1024 + col] = o[r];
      }
    }
  }
}

__global__ __launch_bounds__(256) void qkv_gemm(
    const unsigned short* __restrict__ hsb,
    const unsigned short* __restrict__ WT, const float* __restrict__ bq,
    const float* __restrict__ bk, const float* __restrict__ bv,
    unsigned short* __restrict__ QF, unsigned short* __restrict__ KF,
    unsigned short* __restrict__ VF) {
  if (blockIdx.z == 0) {
    gemm_mfma_body<0>(hsb, WT, bq, QF);
  } else if (blockIdx.z == 1) {
    gemm_mfma_body<1>(hsb, WT + 1024 * 1024, bk, KF);
  } else {
    gemm_mfma_body<2>(hsb, WT + 2 * 1024 * 1024, bv, VF);
  }
}

__global__ __launch_bounds__(256) void out_gemm(
    const unsigned short* __restrict__ ctxb,
    const unsigned short* __restrict__ WoT, const float* __restrict__ bo,
    float* __restrict__ out) {
  gemm_mfma_body<3>(ctxb, WoT, bo, out);
}

// ---------------- fused attention, single transposed layout ------------------
// (R7 body + R9: s_setprio(1) around the three MFMA-dense regions. T5
// mechanism: 2 independent blocks/CU sit at different phases; boosting the
// MFMA-issuing wave over the other block's VMEM/VALU issue is the m191 attn
// regime, +4-7% there; bounded downside.)
// 1024 threads / 16 waves. Wave w owns key-tiles 6w..6w+5 (keys 96w..96w+95);
// lane holds q=lc, keys 16j+4*quad+r. Slot s>=1 of P2u holds p^T (f16) for
// key-tile s-1; slot 0 = zero halo. LDS P2u is the sole p master.
// Row stride 12 u32 (48B): 8 distinct 16B-aligned bank starts x 2 lanes =
// conflict-free b128/b64 phases; spare cols 8..11 hold PV partials.
__global__ __launch_bounds__(1024)
    __attribute__((amdgpu_waves_per_eu(8))) void attn_kernel(
        const unsigned short* __restrict__ QF,
        const unsigned short* __restrict__ KF,
        const unsigned short* __restrict__ VF, const int* __restrict__ mask,
        const float* __restrict__ kernel_w, unsigned short* __restrict__ ctxb) {
  __shared__ __align__(16) unsigned int P2u[97 * 192];  // 74,496 B, rows 12 u32
  __shared__ unsigned int kvb[48];                      // packed key-valid bits
  __shared__ float red_a[16][16];
  __shared__ float red_b[16][16];
  __shared__ float wext[48];  // band weights, wext[16+d]=wr[d], else 0

  const int t = threadIdx.x;
  const int lane = t & 63;
  const int w = t >> 6;        // wave id 0..15
  const int quad = lane >> 4;  // 0..3
  const int lc = lane & 15;
  const int b = blockIdx.z, h = blockIdx.y;
  const int q0 = blockIdx.x * 16;

  // key-valid bitmask via per-wave ballot
  {
    unsigned long long bal = __ballot(mask[b * LL + t] > 0);  // keys 0..1023
    if (lane == 0) {
      kvb[2 * w] = (unsigned int)bal;
      kvb[2 * w + 1] = (unsigned int)(bal >> 32);
    }
  }
  if (w < 8) {  // keys 1024..1535 (wave-uniform branch)
    unsigned long long bal = __ballot(mask[b * LL + 1024 + t] > 0);
    if (lane == 0) {
      kvb[32 + 2 * w] = (unsigned int)bal;
      kvb[33 + 2 * w] = (unsigned int)(bal >> 32);
    }
  }
  // zero halo slot 0 of P2u (192 u32 incl. spare cols)
  if (t < 192) P2u[t] = 0;
  // reversed-softmax smoothing weights -> extended band array
  {
    float k0 = kernel_w[0], k1 = kernel_w[1], k2 = kernel_w[2],
          k3 = kernel_w[3], k4 = kernel_w[4];
    float km = fmaxf(fmaxf(fmaxf(k0, k1), fmaxf(k2, k3)), k4);
    float e0 = __expf(k0 - km), e1 = __expf(k1 - km), e2 = __expf(k2 - km),
          e3 = __expf(k3 - km), e4 = __expf(k4 - km);
    float es = e0 + e1 + e2 + e3 + e4;
    // wr[d] = softmax(w)[4-d]; ps[i] = sum_d wr[d]*p[i-d]
    if (t < 48) {
      float v = 0.f;
      if (t == 16) v = e4 / es;
      if (t == 17) v = e3 / es;
      if (t == 18) v = e2 / es;
      if (t == 19) v = e1 / es;
      if (t == 20) v = e0 / es;
      wext[t] = v;
    }
  }
  __syncthreads();  // S1: kvb, halo, wext visible

  // constant band A-fragment (f16): A[m=lc][k=quad*8+jj] = wr[lc+16-k]
  f16x8 afb;
  {
    const int kb = lc + 32 - quad * 8;  // wext index for jj=0
    uint4 uu;
    uu.x = pkrtz(wext[kb], wext[kb - 1]);
    uu.y = pkrtz(wext[kb - 2], wext[kb - 3]);
    uu.z = pkrtz(wext[kb - 4], wext[kb - 5]);
    uu.w = pkrtz(wext[kb - 6], wext[kb - 7]);
    afb = __builtin_bit_cast(f16x8, uu);
  }

  // ---- phase 1+2 fused: scores MFMA -> masked exp -> pack -> store e~.
  unsigned int* const pwb = &P2u[((6 * w + 1) * 16 + lc) * 12 + 2 * quad];
  unsigned int mA = 0u;
  {
    const unsigned short* qfb =
        QF + (((size_t)(b * HH + h) * 96 + (q0 >> 4)) * 2) * 512 + lane * 8;
    const bf16x8 qb0 = ldb8(qfb);
    const bf16x8 qb1 = ldb8(qfb + 512);
    const unsigned short* kfb =
        KF + (((size_t)(b * HH + h) * 96 + 6 * w) * 2) * 512 + lane * 8;
    float s = 0.f;
    __builtin_amdgcn_s_setprio(1);
#pragma unroll
    for (int j = 0; j < 6; ++j) {
      bf16x8 ka0 = ldb8(kfb + j * 1024);
      bf16x8 ka1 = ldb8(kfb + j * 1024 + 512);
      f32x4 acc = {0.f, 0.f, 0.f, 0.f};
      acc = __builtin_amdgcn_mfma_f32_16x16x32_bf16(ka0, qb0, acc, 0, 0, 0);
      acc = __builtin_amdgcn_mfma_f32_16x16x32_bf16(ka1, qb1, acc, 0, 0, 0);
      const int kb16 = 16 * j + 4 * quad;  // (96w + kb16) & 31 == kb16 & 31
      const unsigned int w4 = (kvb[3 * w + (kb16 >> 5)] >> (kb16 & 31)) & 0xFu;
      mA |= w4 << (4 * j);
      float e0 = (w4 & 1u) ? __expf(acc[0]) : 0.f;
      float e1 = (w4 & 2u) ? __expf(acc[1]) : 0.f;
      float e2 = (w4 & 4u) ? __expf(acc[2]) : 0.f;
      float e3 = (w4 & 8u) ? __expf(acc[3]) : 0.f;
      uint2 u;
      u.x = pkrtz(e0, e1);
      u.y = pkrtz(e2, e3);
      *(uint2*)(pwb + j * 192) = u;
      s += (e0 + e1) + (e2 + e3);
    }
    __builtin_amdgcn_s_setprio(0);
    s += __shfl_xor(s, 16, 64);
    s += __shfl_xor(s, 32, 64);
    if (lane < 16) red_a[w][lane] = s;
  }
  __syncthreads();  // S3: P2u (e~) + red_a visible

  // ---- phase 3: 3 diffusion steps; smooth = f16 MFMA vs constant band frag.
  const unsigned int ones2 = 0x3C003C00u;  // f16 {1,1}
  const unsigned int* const prb =
      &P2u[((6 * w + (quad >> 1)) * 16 + lc) * 12 + (quad & 1) * 4];
  float inv = 0.f;
#pragma unroll
  for (int step = 0; step < 3; ++step) {
    unsigned int s_pk[12];  // masked smoothed p, packed f16 pairs
    float sum = 0.f;
    __builtin_amdgcn_s_setprio(1);
#pragma unroll
    for (int j = 0; j < 6; ++j) {
      f16x8 bfr = ldh8u(prb + j * 192);
      f32x4 z = {0.f, 0.f, 0.f, 0.f};
      f32x4 ps = __builtin_amdgcn_mfma_f32_16x16x32_f16(afb, bfr, z, 0, 0, 0);
      const unsigned int w4 = (mA >> (4 * j)) & 0xFu;
      float p0 = (w4 & 1u) ? ps[0] : 0.f;
      float p1 = (w4 & 2u) ? ps[1] : 0.f;
      float p2 = (w4 & 4u) ? ps[2] : 0.f;
      float p3 = (w4 & 8u) ? ps[3] : 0.f;
      s_pk[2 * j] = pkrtz(p0, p1);
      s_pk[2 * j + 1] = pkrtz(p2, p3);
      sum = fdot2u(s_pk[2 * j], ones2, sum);
      sum = fdot2u(s_pk[2 * j + 1], ones2, sum);
    }
    __builtin_amdgcn_s_setprio(0);
    sum += __shfl_xor(sum, 16, 64);
    sum += __shfl_xor(sum, 32, 64);
    if (step == 0) {  // softmax denom (red_a stable until step 1's write)
      float tot0 = 0.f;
#pragma unroll
      for (int ww = 0; ww < 16; ++ww) tot0 += red_a[ww][lc];
      inv = 1.f / tot0;
    }
    if (lane < 16) {
      if (step & 1)
        red_a[w][lane] = sum;
      else
        red_b[w][lane] = sum;
    }
    __syncthreads();  // B1: all P2u reads of this step done; partials ready
    float tot = 0.f;
#pragma unroll
    for (int ww = 0; ww < 16; ++ww)
      tot += (step & 1) ? red_a[ww][lc] : red_b[ww][lc];
    // new_p = p_old*cmul + (s_pk*cinv)*cps
    f16x2 cmul, cinv, cps;
    if (step == 0) {
      const float sps = tot * inv;  // sum(ps) in normalized domain
      const float pinv = 0.02f / (sps + 1e-9f);
      const _Float16 hc = (_Float16)(0.98f * inv);
      const _Float16 hi = (_Float16)inv;
      const _Float16 hp = (_Float16)pinv;
      cmul = (f16x2){hc, hc};
      cinv = (f16x2){hi, hi};
      cps = (f16x2){hp, hp};
    } else {
      const float pinv = 0.02f / (tot + 1e-9f);
      const _Float16 hp = (_Float16)pinv;
      cmul = (f16x2){(_Float16)0.98f, (_Float16)0.98f};
      cinv = (f16x2){(_Float16)1.f, (_Float16)1.f};
      cps = (f16x2){hp, hp};
    }
#pragma unroll
    for (int j = 0; j < 6; ++j) {
      uint2 po = *(const uint2*)(pwb + j * 192);  // own slots only
      f16x2 p0h = __builtin_bit_cast(f16x2, po.x);
      f16x2 p1h = __builtin_bit_cast(f16x2, po.y);
      f16x2 s0h = __builtin_bit_cast(f16x2, s_pk[2 * j]);
      f16x2 s1h = __builtin_bit_cast(f16x2, s_pk[2 * j + 1]);
      p0h = p0h * cmul + (s0h * cinv) * cps;
      p1h = p1h * cmul + (s1h * cinv) * cps;
      uint2 nu;
      nu.x = __builtin_bit_cast(unsigned int, p0h);
      nu.y = __builtin_bit_cast(unsigned int, p1h);
      *(uint2*)(pwb + j * 192) = nu;
    }
    __syncthreads();  // B2: new p visible for next step / PV
  }

  // ---- phase 4: PV via f16 MFMA; A = p frags from P2u, B = V frags (f16).
  // 4 col-groups (cg=w&3, hd cols cg*16+lc) x 4 key-quarters (kt=w>>2,
  // 12 windows of 32 keys each). Partials exchanged through the SPARE
  // columns (u32 8..11) of P2u rows — disjoint from data cols, no barrier
  // needed between PV reads and partial stores.
  const int cg = w & 3;
  const int kt = w >> 2;
  const int cidx = cg * 16 + lc;
  const int li = (cg * 4 + quad) * 16 + lc;  // 0..255
  const unsigned short* vfb =
      VF + ((((size_t)(b * HH + h) * 4 + cg) * 48 + 12 * kt) * 512) + lane * 8;
  const unsigned int* const pvb =
      &P2u[((24 * kt + 1 + (quad >> 1)) * 16 + lc) * 12 + (quad & 1) * 4];
  f32x4 oacc = {0.f, 0.f, 0.f, 0.f};
  __builtin_amdgcn_s_setprio(1);
#pragma unroll
  for (int g = 0; g < 6; ++g) {
#pragma unroll
    for (int c = 0; c < 2; ++c) {
      f16x8 pa = ldh8u(pvb + (4 * g + 2 * c) * 192);
      f16x8 vf =
          __builtin_bit_cast(f16x8, *(const uint4*)(vfb + (2 * g + c) * 512));
      oacc = __builtin_amdgcn_mfma_f32_16x16x32_f16(pa, vf, oacc, 0, 0, 0);
    }
  }
  __builtin_amdgcn_s_setprio(0);
  if (kt > 0) {
    float* sp = (float*)&P2u[((kt - 1) * 256 + li) * 12 + 8];
    *(float4*)sp = make_float4(oacc[0], oacc[1], oacc[2], oacc[3]);
  }
  __syncthreads();  // partials visible (PV data reads already done per-wave)
  if (kt == 0) {
    float o[4] = {oacc[0], oacc[1], oacc[2], oacc[3]};
#pragma unroll
    for (int p = 0; p < 3; ++p) {
      const float4 prr = *(const float4*)&P2u[(p * 256 + li) * 12 + 8];
      o[0] += prr.x;
      o[1] += prr.y;
      o[2] += prr.z;
      o[3] += prr.w;
    }
#pragma unroll
    for (int r = 0; r < 4; ++r)
      ctxb[((size_t)(b * LL + q0 + quad * 4 + r)) * PP + h * HDD + cidx] =
          f2b(o[r]);
  }
}

extern "C" void kernel_launch(void* const* d_in, const int* in_sizes, int n_in,
                              void* d_out, int out_size, void* d_ws,
                              size_t ws_size, hipStream_t stream) {
  const float* hs = (const float*)d_in[0];
  const int* mask = (const int*)d_in[1];
  const float* Wq = (const float*)d_in[2];
  const float* bq = (const float*)d_in[3];
  const float* Wk = (const float*)d_in[4];
  const float* bk = (const float*)d_in[5];
  const float* Wv = (const float*)d_in[6];
  const float* bv = (const float*)d_in[7];
  const float* Wo = (const float*)d_in[8];
  const float* bo = (const float*)d_in[9];
  const float* kw = (const float*)d_in[10];

  const size_t NBLP = (size_t)BB * LL * PP;    // 3,145,728 elems
  unsigned short* QF = (unsigned short*)d_ws;  // Q fragment-linear
  unsigned short* KF = QF + NBLP;              // K fragment-linear
  unsigned short* VF = KF + NBLP;              // V fragment-linear (f16)
  unsigned short* ctxb = VF + NBLP;            // bf16 ctx
  unsigned short* hsb = ctxb + NBLP;
  unsigned short* WT = hsb + NBLP;  // 4 x [1024][1024] bf16 (n-major)

  dim3 blk(256);
  prep<<<dim3(2560), blk, 0, stream>>>(hs, hsb, Wq, Wk, Wv, Wo, WT);
  qkv_gemm<<<dim3(8, 24, 3), blk, 0, stream>>>(hsb, WT, bq, bk, bv, QF, KF, VF);
  attn_kernel<<<dim3(96, 16, 2), dim3(1024), 0, stream>>>(QF, KF, VF, mask, kw,
                                                          ctxb);
  out_gemm<<<dim3(8, 24, 1), blk, 0, stream>>>(ctxb, WT + 3 * 1024 * 1024, bo,
                                               (float*)d_out);
}

// Round 10
// 229.753 us; speedup vs baseline: 1.1623x; 1.0388x over previous
//
#include <hip/hip_runtime.h>

#define BB 2
#define LL 1536
#define DD 1024
#define HH 16
#define HDD 64
#define PP 1024

typedef __attribute__((ext_vector_type(8))) __bf16 bf16x8;
typedef __attribute__((ext_vector_type(4))) float f32x4;
typedef __attribute__((ext_vector_type(2))) float f32x2;
typedef _Float16 f16x2 __attribute__((ext_vector_type(2)));
typedef _Float16 f16x8 __attribute__((ext_vector_type(8)));

__device__ __forceinline__ unsigned short f2b(float f) {
  unsigned int x = __builtin_bit_cast(unsigned int, f);
  unsigned int r = (x + 0x7FFFu + ((x >> 16) & 1u)) >> 16;
  return (unsigned short)r;
}
__device__ __forceinline__ bf16x8 ldb8(const unsigned short* p) {
  return __builtin_bit_cast(bf16x8, *(const uint4*)p);
}
__device__ __forceinline__ f16x8 ldh8u(const unsigned int* p) {
  return __builtin_bit_cast(f16x8, *(const uint4*)p);
}
__device__ __forceinline__ unsigned int pkrtz(float lo, float hi) {
  return __builtin_bit_cast(unsigned int, __builtin_amdgcn_cvt_pkrtz(lo, hi));
}
// masked f16-pair dot accumulate: c += a.x*b.x + a.y*b.y
__device__ __forceinline__ float fdot2u(unsigned int a, unsigned int ones,
                                        float c) {
#if __has_builtin(__builtin_amdgcn_fdot2)
  return __builtin_amdgcn_fdot2(__builtin_bit_cast(f16x2, a),
                                __builtin_bit_cast(f16x2, ones), c, false);
#else
  f16x2 x = __builtin_bit_cast(f16x2, a);
  return c + (float)x.x + (float)x.y;
#endif
}
// async global->LDS, 16B per lane; lds dst = wave-uniform base + lane*16
__device__ __forceinline__ void gl_lds16(const unsigned short* g,
                                         unsigned short* l) {
  __builtin_amdgcn_global_load_lds(
      (const __attribute__((address_space(1))) void*)g,
      (__attribute__((address_space(3))) void*)l, 16, 0, 0);
}

// ---------------- prep: cast hs -> bf16 AND transpose 4x W -> WT bf16 -------
__global__ __launch_bounds__(256) void prep(
    const float* __restrict__ hs, unsigned short* __restrict__ hsb,
    const float* __restrict__ Wq, const float* __restrict__ Wk,
    const float* __restrict__ Wv, const float* __restrict__ Wo,
    unsigned short* __restrict__ WT) {
  const int bid = blockIdx.x;
  const int t = threadIdx.x;
  if (bid < 1536) {
    const int idx = bid * 2048 + t * 8;
    float4 a = *(const float4*)(hs + idx);
    float4 b = *(const float4*)(hs + idx + 4);
    uint4 u;
    u.x = (unsigned int)f2b(a.x) | ((unsigned int)f2b(a.y) << 16);
    u.y = (unsigned int)f2b(a.z) | ((unsigned int)f2b(a.w) << 16);
    u.z = (unsigned int)f2b(b.x) | ((unsigned int)f2b(b.y) << 16);
    u.w = (unsigned int)f2b(b.z) | ((unsigned int)f2b(b.w) << 16);
    *(uint4*)(hsb + idx) = u;
  } else {
    __shared__ float tile[64][68];
    const int t2 = bid - 1536;
    const int z = t2 >> 8;
    const int bx = t2 & 15, by = (t2 >> 4) & 15;
    const float* W = (z == 0) ? Wq : (z == 1) ? Wk : (z == 2) ? Wv : Wo;
    unsigned short* O = WT + (size_t)z * 1024 * 1024;
    const int r0 = by * 64;  // k rows
    const int c0 = bx * 64;  // n cols
#pragma unroll
    for (int i = 0; i < 4; ++i) {
      const int row = (t >> 4) + i * 16;
      const int col = (t & 15) * 4;
      *(float4*)&tile[row][col] =
          *(const float4*)&W[(size_t)(r0 + row) * 1024 + c0 + col];
    }
    __syncthreads();
#pragma unroll
    for (int i = 0; i < 4; ++i) {
      const int n = (t >> 4) + i * 16;
      const int k4 = (t & 15) * 4;
      uint2 u;
      u.x = (unsigned int)f2b(tile[k4 + 0][n]) |
            ((unsigned int)f2b(tile[k4 + 1][n]) << 16);
      u.y = (unsigned int)f2b(tile[k4 + 2][n]) |
            ((unsigned int)f2b(tile[k4 + 3][n]) << 16);
      *(uint2*)&O[(size_t)(c0 + n) * 1024 + r0 + k4] = u;
    }
  }
}

// ---------------- bf16 MFMA GEMM: C[M,1024] = A[M,1024] @ Bt[1024,1024]^T ----
// 128x128 tile, BK=32, 4 waves, 4x4 MFMA/wave. R7-exact single-buffer
// 2-barrier m97-structure (R8's dbuf regressed; see R9 comment history).
// MODE 0: Q fragment-linear *0.125. MODE 1: K fragment-linear. MODE 2: V
// fragment-linear (f16 — PV consumes f16). MODE 3: fp32 row-major.
template <int MODE>
__device__ __forceinline__ void gemm_mfma_body(
    const unsigned short* __restrict__ A, const unsigned short* __restrict__ Bt,
    const float* __restrict__ bias, void* __restrict__ Cout) {
  __shared__ unsigned short As[128 * 32];
  __shared__ unsigned short Bs[128 * 32];
  const int t = threadIdx.x;
  const int lane = t & 63;
  const int w = t >> 6;
  const int quad = lane >> 4;
  const int lc = lane & 15;
  const int m0 = blockIdx.y * 128, n0 = blockIdx.x * 128;

  const int sr = lane >> 2;       // row within 16-row group
  const int sk = (lane & 3) * 8;  // k element offset
  const unsigned short* ga0 = A + (size_t)(m0 + w * 32 + sr) * 1024 + sk;
  const unsigned short* ga1 = ga0 + 16 * 1024;
  const unsigned short* gb0 = Bt + (size_t)(n0 + w * 32 + sr) * 1024 + sk;
  const unsigned short* gb1 = gb0 + 16 * 1024;
  unsigned short* la0 = As + w * 1024;
  unsigned short* la1 = As + w * 1024 + 512;
  unsigned short* lb0 = Bs + w * 1024;
  unsigned short* lb1 = Bs + w * 1024 + 512;

  const int mrow0 = (w >> 1) * 64, ncol0 = (w & 1) * 64;

  f32x4 acc[4][4];
#pragma unroll
  for (int i = 0; i < 4; ++i)
#pragma unroll
    for (int j = 0; j < 4; ++j) acc[i][j] = (f32x4){0.f, 0.f, 0.f, 0.f};

  for (int k0 = 0; k0 < 1024; k0 += 32) {
    __syncthreads();  // previous iter's ds_reads done before overwrite
    gl_lds16(ga0 + k0, la0);
    gl_lds16(ga1 + k0, la1);
    gl_lds16(gb0 + k0, lb0);
    gl_lds16(gb1 + k0, lb1);
    __syncthreads();  // staged data visible
    bf16x8 af[4], bfr[4];
#pragma unroll
    for (int i = 0; i < 4; ++i)
      af[i] = ldb8(&As[(mrow0 + i * 16 + lc) * 32 + quad * 8]);
#pragma unroll
    for (int j = 0; j < 4; ++j)
      bfr[j] = ldb8(&Bs[(ncol0 + j * 16 + lc) * 32 + quad * 8]);
#pragma unroll
    for (int i = 0; i < 4; ++i)
#pragma unroll
      for (int j = 0; j < 4; ++j)
        acc[i][j] = __builtin_amdgcn_mfma_f32_16x16x32_bf16(af[i], bfr[j],
                                                            acc[i][j], 0, 0, 0);
  }

#pragma unroll
  for (int i = 0; i < 4; ++i) {
    const int row0 = m0 + mrow0 + i * 16 + quad * 4;  // rows row0..row0+3
#pragma unroll
    for (int jj = 0; jj < 4; ++jj) {
      const int col = n0 + ncol0 + jj * 16 + lc;
      const float bz = bias[col];
      float o[4];
#pragma unroll
      for (int r = 0; r < 4; ++r) o[r] = acc[i][jj][r] + bz;
      if constexpr (MODE == 0) {
        // Q fragment-linear: QF[(bh*96+qt)*2+f][qk*16+m][8], scale 0.125
        const int bb = row0 / LL;
        const int ql = row0 - bb * LL;  // q local; %16 == quad*4
        const int qt = ql >> 4;
        const int m = ql & 15;
        const int hh = col >> 6;
        const int hd = col & 63;
        const int f = hd >> 5;
        const int qk = (hd >> 3) & 3;
        const int j = hd & 7;
        unsigned short* QF = (unsigned short*)Cout;
        const size_t base = (((size_t)(bb * HH + hh) * 96 + qt) * 2 + f) * 512 +
                            (qk * 16 + m) * 8 + j;
#pragma unroll
        for (int r = 0; r < 4; ++r) QF[base + r * 8] = f2b(o[r] * 0.125f);
      } else if constexpr (MODE == 1) {
        // K fragment-linear: key=row, tile=key/16, m=key%16, col-> f,qk,j
        const int bb = row0 / LL;
        const int kl = row0 - bb * LL;  // key local, %16 == quad*4
        const int ktl = kl >> 4;
        const int m = kl & 15;
        const int hh = col >> 6;
        const int hd = col & 63;
        const int f = hd >> 5;
        const int qk = (hd >> 3) & 3;
        const int j = hd & 7;
        unsigned short* KF = (unsigned short*)Cout;
        const size_t base =
            (((size_t)(bb * HH + hh) * 96 + ktl) * 2 + f) * 512 +
            (qk * 16 + m) * 8 + j;
#pragma unroll
        for (int r = 0; r < 4; ++r) KF[base + r * 8] = f2b(o[r]);
      } else if constexpr (MODE == 2) {
        // V fragment-linear, f16: r=0..3 -> 4 consecutive j -> one uint2 store
        const int bb = row0 / LL;
        const int kl = row0 - bb * LL;  // key local of r=0
        const int hh = col >> 6;
        const int hd = col & 63;
        const int hg = hd >> 4;
        const int lcv = hd & 15;
        const int tile = (kl >> 5);  // gg*2 + c
        const int qv = (kl >> 3) & 3;
        const int j0 = kl & 7;  // 0 or 4
        unsigned short* VF = (unsigned short*)Cout;
        const size_t base = (((size_t)(bb * HH + hh) * 4 + hg) * 48 + tile) * 512 +
                            (qv * 16 + lcv) * 8 + j0;
        uint2 u;
        u.x = pkrtz(o[0], o[1]);
        u.y = pkrtz(o[2], o[3]);
        *(uint2*)&VF[base] = u;
      } else {
#pragma unroll
        for (int r = 0; r < 4; ++r)
          ((float*)Cout)[(size_t)(row0 + r) * 1024 + col] = o[r];
      }
    }
  }
}

__global__ __launch_bounds__(256) void qkv_gemm(
    const unsigned short* __restrict__ hsb,
    const unsigned short* __restrict__ WT, const float* __restrict__ bq,
    const float* __restrict__ bk, const float* __restrict__ bv,
    unsigned short* __restrict__ QF, unsigned short* __restrict__ KF,
    unsigned short* __restrict__ VF) {
  if (blockIdx.z == 0) {
    gemm_mfma_body<0>(hsb, WT, bq, QF);
  } else if (blockIdx.z == 1) {
    gemm_mfma_body<1>(hsb, WT + 1024 * 1024, bk, KF);
  } else {
    gemm_mfma_body<2>(hsb, WT + 2 * 1024 * 1024, bv, VF);
  }
}

__global__ __launch_bounds__(256) void out_gemm(
    const unsigned short* __restrict__ ctxb,
    const unsigned short* __restrict__ WoT, const float* __restrict__ bo,
    float* __restrict__ out) {
  gemm_mfma_body<3>(ctxb, WoT, bo, out);
}

// ---------------- fused attention, single transposed layout ------------------
// 1024 threads / 16 waves. Wave w owns key-tiles 6w..6w+5 (keys 96w..96w+95);
// lane holds q=lc, keys 16j+4*quad+r. Slot s>=1 of P2u holds p^T (f16) for
// key-tile s-1; slot 0 = zero halo. LDS P2u is the sole p master.
// Row stride 12 u32 (48B): 8 distinct 16B-aligned bank starts x 2 lanes =
// conflict-free b128/b64 phases; spare cols 8..11 hold PV partials.
// R10: (a) setprio REVERTED (R9: attn 103.5->106.5, lockstep-barrier regime
// = m190 null case, not m191). (b) S1 barrier DELETED: key-valid bits now
// from two wave-local ballots (wave w only needs keys 96w..96w+95) — no kvb
// LDS, no producer barrier; afb build moved after S3 (first use is phase 3;
// wext visibility covered by S3). Barriers 9 -> 8. (c) reduction buffers
// transposed to red[16 q][20 ww] (80B rows, 16B-aligned, <=2-way banks):
// cross-wave reduces read 4x ds_read_b128 instead of 16x strided b32
// (4 occurrences, ~48 fewer LDS issues/thread).
__global__ __launch_bounds__(1024)
    __attribute__((amdgpu_waves_per_eu(8))) void attn_kernel(
        const unsigned short* __restrict__ QF,
        const unsigned short* __restrict__ KF,
        const unsigned short* __restrict__ VF, const int* __restrict__ mask,
        const float* __restrict__ kernel_w, unsigned short* __restrict__ ctxb) {
  __shared__ __align__(16) unsigned int P2u[97 * 192];  // 74,496 B, rows 12 u32
  __shared__ __align__(16) float red_a[16][20];
  __shared__ __align__(16) float red_b[16][20];
  __shared__ float wext[48];  // band weights, wext[16+d]=wr[d], else 0

  const int t = threadIdx.x;
  const int lane = t & 63;
  const int w = t >> 6;        // wave id 0..15
  const int quad = lane >> 4;  // 0..3
  const int lc = lane & 15;
  const int b = blockIdx.z, h = blockIdx.y;
  const int q0 = blockIdx.x * 16;

  // wave-local key-valid bits: wave w owns keys 96w..96w+95. Two ballots,
  // no LDS, no barrier. bal0 = keys +0..63; bal1 bits 0..31 = keys +64..95.
  unsigned int mA;
  {
    unsigned long long bal0 = __ballot(mask[b * LL + 96 * w + lane] > 0);
    int mv = (lane < 32) ? mask[b * LL + 96 * w + 64 + lane] : 0;
    unsigned long long bal1 = __ballot(mv > 0);
    mA = 0u;
#pragma unroll
    for (int j = 0; j < 6; ++j) {
      const int kb16 = 16 * j + 4 * quad;
      const unsigned int w4 =
          (j < 4) ? (unsigned int)((bal0 >> kb16) & 0xFull)
                  : (unsigned int)((bal1 >> (kb16 - 64)) & 0xFull);
      mA |= w4 << (4 * j);
    }
  }
  // zero halo slot 0 of P2u (192 u32 incl. spare cols)
  if (t < 192) P2u[t] = 0;
  // reversed-softmax smoothing weights -> extended band array
  {
    float k0 = kernel_w[0], k1 = kernel_w[1], k2 = kernel_w[2],
          k3 = kernel_w[3], k4 = kernel_w[4];
    float km = fmaxf(fmaxf(fmaxf(k0, k1), fmaxf(k2, k3)), k4);
    float e0 = __expf(k0 - km), e1 = __expf(k1 - km), e2 = __expf(k2 - km),
          e3 = __expf(k3 - km), e4 = __expf(k4 - km);
    float es = e0 + e1 + e2 + e3 + e4;
    // wr[d] = softmax(w)[4-d]; ps[i] = sum_d wr[d]*p[i-d]
    if (t < 48) {
      float v = 0.f;
      if (t == 16) v = e4 / es;
      if (t == 17) v = e3 / es;
      if (t == 18) v = e2 / es;
      if (t == 19) v = e1 / es;
      if (t == 20) v = e0 / es;
      wext[t] = v;
    }
  }

  // ---- phase 1+2 fused: scores MFMA -> masked exp -> pack -> store e~.
  // (No barrier needed before this: P2u writes go to own slots >=1; halo
  // writes to slot 0 only; wext first read after S3.)
  unsigned int* const pwb = &P2u[((6 * w + 1) * 16 + lc) * 12 + 2 * quad];
  {
    const unsigned short* qfb =
        QF + (((size_t)(b * HH + h) * 96 + (q0 >> 4)) * 2) * 512 + lane * 8;
    const bf16x8 qb0 = ldb8(qfb);
    const bf16x8 qb1 = ldb8(qfb + 512);
    const unsigned short* kfb =
        KF + (((size_t)(b * HH + h) * 96 + 6 * w) * 2) * 512 + lane * 8;
    float s = 0.f;
#pragma unroll
    for (int j = 0; j < 6; ++j) {
      bf16x8 ka0 = ldb8(kfb + j * 1024);
      bf16x8 ka1 = ldb8(kfb + j * 1024 + 512);
      f32x4 acc = {0.f, 0.f, 0.f, 0.f};
      acc = __builtin_amdgcn_mfma_f32_16x16x32_bf16(ka0, qb0, acc, 0, 0, 0);
      acc = __builtin_amdgcn_mfma_f32_16x16x32_bf16(ka1, qb1, acc, 0, 0, 0);
      const unsigned int w4 = (mA >> (4 * j)) & 0xFu;
      float e0 = (w4 & 1u) ? __expf(acc[0]) : 0.f;
      float e1 = (w4 & 2u) ? __expf(acc[1]) : 0.f;
      float e2 = (w4 & 4u) ? __expf(acc[2]) : 0.f;
      float e3 = (w4 & 8u) ? __expf(acc[3]) : 0.f;
      uint2 u;
      u.x = pkrtz(e0, e1);
      u.y = pkrtz(e2, e3);
      *(uint2*)(pwb + j * 192) = u;
      s += (e0 + e1) + (e2 + e3);
    }
    s += __shfl_xor(s, 16, 64);
    s += __shfl_xor(s, 32, 64);
    if (lane < 16) red_a[lane][w] = s;
  }
  __syncthreads();  // S3: P2u (e~) + red_a + wext + halo visible

  // constant band A-fragment (f16): A[m=lc][k=quad*8+jj] = wr[lc+16-k]
  f16x8 afb;
  {
    const int kb = lc + 32 - quad * 8;  // wext index for jj=0
    uint4 uu;
    uu.x = pkrtz(wext[kb], wext[kb - 1]);
    uu.y = pkrtz(wext[kb - 2], wext[kb - 3]);
    uu.z = pkrtz(wext[kb - 4], wext[kb - 5]);
    uu.w = pkrtz(wext[kb - 6], wext[kb - 7]);
    afb = __builtin_bit_cast(f16x8, uu);
  }

  // ---- phase 3: 3 diffusion steps; smooth = f16 MFMA vs constant band frag.
  const unsigned int ones2 = 0x3C003C00u;  // f16 {1,1}
  const unsigned int* const prb =
      &P2u[((6 * w + (quad >> 1)) * 16 + lc) * 12 + (quad & 1) * 4];
  float inv = 0.f;
#pragma unroll
  for (int step = 0; step < 3; ++step) {
    unsigned int s_pk[12];  // masked smoothed p, packed f16 pairs
    float sum = 0.f;
#pragma unroll
    for (int j = 0; j < 6; ++j) {
      f16x8 bfr = ldh8u(prb + j * 192);
      f32x4 z = {0.f, 0.f, 0.f, 0.f};
      f32x4 ps = __builtin_amdgcn_mfma_f32_16x16x32_f16(afb, bfr, z, 0, 0, 0);
      const unsigned int w4 = (mA >> (4 * j)) & 0xFu;
      float p0 = (w4 & 1u) ? ps[0] : 0.f;
      float p1 = (w4 & 2u) ? ps[1] : 0.f;
      float p2 = (w4 & 4u) ? ps[2] : 0.f;
      float p3 = (w4 & 8u) ? ps[3] : 0.f;
      s_pk[2 * j] = pkrtz(p0, p1);
      s_pk[2 * j + 1] = pkrtz(p2, p3);
      sum = fdot2u(s_pk[2 * j], ones2, sum);
      sum = fdot2u(s_pk[2 * j + 1], ones2, sum);
    }
    sum += __shfl_xor(sum, 16, 64);
    sum += __shfl_xor(sum, 32, 64);
    if (step == 0) {  // softmax denom (red_a stable until step 1's write)
      const float* rp = &red_a[lc][0];
      float4 a0 = *(const float4*)(rp);
      float4 a1 = *(const float4*)(rp + 4);
      float4 a2 = *(const float4*)(rp + 8);
      float4 a3 = *(const float4*)(rp + 12);
      float tot0 = ((a0.x + a0.y) + (a0.z + a0.w)) +
                   ((a1.x + a1.y) + (a1.z + a1.w)) +
                   ((a2.x + a2.y) + (a2.z + a2.w)) +
                   ((a3.x + a3.y) + (a3.z + a3.w));
      inv = 1.f / tot0;
    }
    if (lane < 16) {
      if (step & 1)
        red_a[lane][w] = sum;
      else
        red_b[lane][w] = sum;
    }
    __syncthreads();  // B1: all P2u reads of this step done; partials ready
    const float* rp = (step & 1) ? &red_a[lc][0] : &red_b[lc][0];
    float4 a0 = *(const float4*)(rp);
    float4 a1 = *(const float4*)(rp + 4);
    float4 a2 = *(const float4*)(rp + 8);
    float4 a3 = *(const float4*)(rp + 12);
    const float tot =
        ((a0.x + a0.y) + (a0.z + a0.w)) + ((a1.x + a1.y) + (a1.z + a1.w)) +
        ((a2.x + a2.y) + (a2.z + a2.w)) + ((a3.x + a3.y) + (a3.z + a3.w));
    // new_p = p_old*cmul + (s_pk*cinv)*cps
    f16x2 cmul, cinv, cps;
    if (step == 0) {
      const float sps = tot * inv;  // sum(ps) in normalized domain
      const float pinv = 0.02f / (sps + 1e-9f);
      const _Float16 hc = (_Float16)(0.98f * inv);
      const _Float16 hi = (_Float16)inv;
      const _Float16 hp = (_Float16)pinv;
      cmul = (f16x2){hc, hc};
      cinv = (f16x2){hi, hi};
      cps = (f16x2){hp, hp};
    } else {
      const float pinv = 0.02f / (tot + 1e-9f);
      const _Float16 hp = (_Float16)pinv;
      cmul = (f16x2){(_Float16)0.98f, (_Float16)0.98f};
      cinv = (f16x2){(_Float16)1.f, (_Float16)1.f};
      cps = (f16x2){hp, hp};
    }
#pragma unroll
    for (int j = 0; j < 6; ++j) {
      uint2 po = *(const uint2*)(pwb + j * 192);  // own slots only
      f16x2 p0h = __builtin_bit_cast(f16x2, po.x);
      f16x2 p1h = __builtin_bit_cast(f16x2, po.y);
      f16x2 s0h = __builtin_bit_cast(f16x2, s_pk[2 * j]);
      f16x2 s1h = __builtin_bit_cast(f16x2, s_pk[2 * j + 1]);
      p0h = p0h * cmul + (s0h * cinv) * cps;
      p1h = p1h * cmul + (s1h * cinv) * cps;
      uint2 nu;
      nu.x = __builtin_bit_cast(unsigned int, p0h);
      nu.y = __builtin_bit_cast(unsigned int, p1h);
      *(uint2*)(pwb + j * 192) = nu;
    }
    __syncthreads();  // B2: new p visible for next step / PV
  }

  // ---- phase 4: PV via f16 MFMA; A = p frags from P2u, B = V frags (f16).
  // 4 col-groups (cg=w&3, hd cols cg*16+lc) x 4 key-quarters (kt=w>>2,
  // 12 windows of 32 keys each). Partials exchanged through the SPARE
  // columns (u32 8..11) of P2u rows — disjoint from data cols, no barrier
  // needed between PV reads and partial stores.
  const int cg = w & 3;
  const int kt = w >> 2;
  const int cidx = cg * 16 + lc;
  const int li = (cg * 4 + quad) * 16 + lc;  // 0..255
  const unsigned short* vfb =
      VF + ((((size_t)(b * HH + h) * 4 + cg) * 48 + 12 * kt) * 512) + lane * 8;
  const unsigned int* const pvb =
      &P2u[((24 * kt + 1 + (quad >> 1)) * 16 + lc) * 12 + (quad & 1) * 4];
  f32x4 oacc = {0.f, 0.f, 0.f, 0.f};
#pragma unroll
  for (int g = 0; g < 6; ++g) {
#pragma unroll
    for (int c = 0; c < 2; ++c) {
      f16x8 pa = ldh8u(pvb + (4 * g + 2 * c) * 192);
      f16x8 vf =
          __builtin_bit_cast(f16x8, *(const uint4*)(vfb + (2 * g + c) * 512));
      oacc = __builtin_amdgcn_mfma_f32_16x16x32_f16(pa, vf, oacc, 0, 0, 0);
    }
  }
  if (kt > 0) {
    float* sp = (float*)&P2u[((kt - 1) * 256 + li) * 12 + 8];
    *(float4*)sp = make_float4(oacc[0], oacc[1], oacc[2], oacc[3]);
  }
  __syncthreads();  // partials visible (PV data reads already done per-wave)
  if (kt == 0) {
    float o[4] = {oacc[0], oacc[1], oacc[2], oacc[3]};
#pragma unroll
    for (int p = 0; p < 3; ++p) {
      const float4 prr = *(const float4*)&P2u[(p * 256 + li) * 12 + 8];
      o[0] += prr.x;
      o[1] += prr.y;
      o[2] += prr.z;
      o[3] += prr.w;
    }
#pragma unroll
    for (int r = 0; r < 4; ++r)
      ctxb[((size_t)(b * LL + q0 + quad * 4 + r)) * PP + h * HDD + cidx] =
          f2b(o[r]);
  }
}

extern "C" void kernel_launch(void* const* d_in, const int* in_sizes, int n_in,
                              void* d_out, int out_size, void* d_ws,
                              size_t ws_size, hipStream_t stream) {
  const float* hs = (const float*)d_in[0];
  const int* mask = (const int*)d_in[1];
  const float* Wq = (const float*)d_in[2];
  const float* bq = (const float*)d_in[3];
  const float* Wk = (const float*)d_in[4];
  const float* bk = (const float*)d_in[5];
  const float* Wv = (const float*)d_in[6];
  const float* bv = (const float*)d_in[7];
  const float* Wo = (const float*)d_in[8];
  const float* bo = (const float*)d_in[9];
  const float* kw = (const float*)d_in[10];

  const size_t NBLP = (size_t)BB * LL * PP;    // 3,145,728 elems
  unsigned short* QF = (unsigned short*)d_ws;  // Q fragment-linear
  unsigned short* KF = QF + NBLP;              // K fragment-linear
  unsigned short* VF = KF + NBLP;              // V fragment-linear (f16)
  unsigned short* ctxb = VF + NBLP;            // bf16 ctx
  unsigned short* hsb = ctxb + NBLP;
  unsigned short* WT = hsb + NBLP;  // 4 x [1024][1024] bf16 (n-major)

  dim3 blk(256);
  prep<<<dim3(2560), blk, 0, stream>>>(hs, hsb, Wq, Wk, Wv, Wo, WT);
  qkv_gemm<<<dim3(8, 24, 3), blk, 0, stream>>>(hsb, WT, bq, bk, bv, QF, KF, VF);
  attn_kernel<<<dim3(96, 16, 2), dim3(1024), 0, stream>>>(QF, KF, VF, mask, kw,
                                                          ctxb);
  out_gemm<<<dim3(8, 24, 1), blk, 0, stream>>>(ctxb, WT + 3 * 1024 * 1024, bo,
                                               (float*)d_out);
}